// Round 17
// baseline (42.914 us; speedup 1.0000x reference)
//
#include <hip/hip_runtime.h>
#include <stdint.h>

#define OUT_F 8192
#define IN_F  8192
#define NGRP  1048576      // OUT*IN/GS
#define BATCH 64
#define KS    8
#define BK    64
#define NSTEP ((IN_F / KS) / BK)   // 16

typedef float f32x4  __attribute__((ext_vector_type(4)));
typedef float f32x16 __attribute__((ext_vector_type(16)));
typedef _Float16 half8_t __attribute__((ext_vector_type(8)));

static __device__ __forceinline__ unsigned int pk_fma_f16(unsigned int a, unsigned int b, unsigned int c) {
  unsigned int d;
  asm("v_pk_fma_f16 %0, %1, %2, %3" : "=v"(d) : "v"(a), "v"(b), "v"(c));
  return d;
}
static __device__ __forceinline__ unsigned int pk16(float a, float b) {
  unsigned short ua = __builtin_bit_cast(unsigned short, (_Float16)a);
  unsigned short ub = __builtin_bit_cast(unsigned short, (_Float16)b);
  return (unsigned int)ua | ((unsigned int)ub << 16);
}

#define GLL16(g, l)                                                         \
  __builtin_amdgcn_global_load_lds(                                         \
      (const __attribute__((address_space(1))) void*)(g),                   \
      (__attribute__((address_space(3))) void*)(l), 16, 0, 0)

// ---- fused pre-pass: x fp32->f16  +  per-2-group {f16x2(s), f16x2(-(64+z)s)} ----
__global__ __launch_bounds__(256) void pre_kernel(const float* __restrict__ x, ushort* __restrict__ xh,
                                                  const float* __restrict__ scale, const float* __restrict__ zero,
                                                  uint32_t* __restrict__ szb) {
  const int b = blockIdx.x;
  if (b < 512) {                      // 512*256 = BATCH*IN_F/4
    const int i = b * 256 + threadIdx.x;
    float4 v = ((const float4*)x)[i];
    ushort4 o;
    o.x = __builtin_bit_cast(unsigned short, (_Float16)v.x);
    o.y = __builtin_bit_cast(unsigned short, (_Float16)v.y);
    o.z = __builtin_bit_cast(unsigned short, (_Float16)v.z);
    o.w = __builtin_bit_cast(unsigned short, (_Float16)v.w);
    ((ushort4*)xh)[i] = o;
  } else {                            // 1024*256 = NGRP/4
    const int i = (b - 512) * 256 + threadIdx.x;
    float4 s = ((const float4*)scale)[i];
    float4 z = ((const float4*)zero)[i];
    uint4 o;
    o.x = pk16(s.x, s.y);
    o.y = pk16(-(64.f + z.x) * s.x, -(64.f + z.y) * s.y);
    o.z = pk16(s.z, s.w);
    o.w = pk16(-(64.f + z.z) * s.z, -(64.f + z.w) * s.w);
    ((uint4*)szb)[i] = o;
  }
}

// ---- main fused dequant + GEMM (R14 schedule; BK=64, KS=8, 40 KB LDS, 4 blocks/CU) ----
// grid 1024: ks = bid&7 (1024 k each), c = bid>>3. Block owns ALL 64 outputs of column c.
// Wave wid: kh = wid&1 (2 of 4 k-slices), mh = (wid>>1)&1 (32 m), nh = wid>>2 (32 o).
// Per step (64 k): x-tile [64][64] f16 (1 gll/wave), W 32 rows reg->dequant->ds_write,
// sz 1 uint4/thread. Final kh-pair sum via LDS scratch.
__global__ __launch_bounds__(512, 6) void hqq_gemm_kernel(
    const int* __restrict__ Wq, const uint32_t* __restrict__ szb,
    const ushort* __restrict__ xh, float* __restrict__ part)
{
  __shared__ ushort xlds[3][64 * 64];   // 8 KB each
  __shared__ ushort blds[2][64 * 64];   // 8 KB each (B tile; reused as reduce scratch)

  const int t    = threadIdx.x;
  const int bid  = blockIdx.x;
  const int ks   = bid & 7;
  const int c    = bid >> 3;
  const int lane = t & 63;
  const int wid  = t >> 6;               // 0..7
  const int kbase = ks * (IN_F / KS);

  // staging ids: lr = t>>4 (0..31) covers ALL 32 Wq rows; i0 = 4 k-ints
  const int lr = t >> 4;
  const int i0 = (t & 15) * 4;
  const int* __restrict__ wq0 = Wq + (size_t)lr * NGRP + (size_t)c * IN_F + kbase + i0;
  const uint8_t* __restrict__ szp =
      (const uint8_t*)szb + ((size_t)c * IN_F + kbase + i0) * 4;
  const int wb0 = (i0 * 2) ^ ((lr & 7) << 4);   // swizzled write byte col (8B aligned)

  // frag ids (32x32 octants)
  const int kh   = wid & 1;
  const int mh   = (wid >> 1) & 1;
  const int nh   = wid >> 2;
  const int ln31 = lane & 31;
  const int koct = lane >> 5;
  const int arow = mh * 32 + ln31;
  const int brow = nh * 32 + ln31;

  f32x16 acc = {0.f, 0.f, 0.f, 0.f, 0.f, 0.f, 0.f, 0.f,
                0.f, 0.f, 0.f, 0.f, 0.f, 0.f, 0.f, 0.f};

  // x: 1 gll per wave, rows wid*8..+7; source pre-swizzled: LDS[m][b]=x[m][b^((m&7)<<4)]
  auto stage_x = [&](int bi, int s) {
    const int m    = wid * 8 + (lane >> 3);
    const int scol = ((lane & 7) * 16) ^ ((m & 7) << 4);
    const ushort* g = xh + (size_t)m * IN_F + kbase + s * BK + (scol >> 1);
    GLL16(g, &xlds[bi][(wid * 8) * 64]);
  };

  auto ldregs = [&](int s, int4& w0, uint4& z4) {
    w0 = *(const int4*)(wq0 + (size_t)s * BK);
    z4 = *(const uint4*)(szp + (size_t)s * (BK * 4));
  };

  // f16 magic: 0x5400 | (v<<4) == 64+v  (nibble at mantissa bits [7:4])
  auto stage_b = [&](int bi, const int4& w0, const uint4& z4) {
    uint8_t* bb = (uint8_t*)&blds[bi][0];
    unsigned tt0 = ((unsigned)w0.y << 16) | (unsigned)w0.x;
    unsigned tt1 = ((unsigned)w0.w << 16) | (unsigned)w0.z;
    uint2 hh, ll;
    hh.x = pk_fma_f16((tt0 & 0x00F000F0u) | 0x54005400u, z4.x, z4.y);
    hh.y = pk_fma_f16((tt1 & 0x00F000F0u) | 0x54005400u, z4.z, z4.w);
    ll.x = pk_fma_f16(((tt0 << 4) & 0x00F000F0u) | 0x54005400u, z4.x, z4.y);
    ll.y = pk_fma_f16(((tt1 << 4) & 0x00F000F0u) | 0x54005400u, z4.z, z4.w);
    *(uint2*)(bb + lr * 128 + wb0)        = hh;   // hi nibble row lr
    *(uint2*)(bb + (lr + 32) * 128 + wb0) = ll;   // lo nibble row lr+32
  };

  // ---- prologue ----
  {
    int4 a0; uint4 z0;
    ldregs(0, a0, z0);
    stage_b(0, a0, z0);               // compiler waits regs(0)
  }
  stage_x(0, 0);
  stage_x(1, 1);
  int4 w0; uint4 z4;
  ldregs(1, w0, z4);                  // regs for stage_b(1)

  int xr0 = 0, xr1 = 1, xr2 = 2;

  #pragma unroll 1
  for (int s = 0; s < NSTEP; ++s) {
    // retire compute(s-1) on all waves; make stage_b(s) ds_writes visible.
    asm volatile("s_waitcnt lgkmcnt(0)" ::: "memory");
    __builtin_amdgcn_s_barrier();

    const bool more2 = (s + 2 < NSTEP);
    int4 n0; uint4 nz;
    if (more2) {
      stage_x(xr2, s + 2);            // 1 gll
      ldregs(s + 2, n0, nz);          // 2 reg loads
    }

    // in-order vmcnt: wait x(s); newer = [x(s+1)1+regs(s+1)2] + [x(s+2)1+regs(s+2)2]
    if (more2)               asm volatile("s_waitcnt vmcnt(6)" ::: "memory");
    else if (s + 1 < NSTEP)  asm volatile("s_waitcnt vmcnt(3)" ::: "memory");
    else                     asm volatile("s_waitcnt vmcnt(0)" ::: "memory");
    __builtin_amdgcn_sched_barrier(0);

    // compute(s): wave's 2 k-slices; 1 A + 1 B ds_read_b128 + 1 32x32x16 MFMA each
    const uint8_t* xb   = (const uint8_t*)&xlds[xr0][0];
    const uint8_t* bbuf = (const uint8_t*)&blds[s & 1][0];
    #pragma unroll
    for (int j = 0; j < 2; ++j) {
      const int kk   = kh * 2 + j;
      const int colb = (kk * 16 + koct * 8) * 2;
      half8_t a = *(const half8_t*)(xb   + arow * 128 + (colb ^ ((arow & 7) << 4)));
      half8_t b = *(const half8_t*)(bbuf + brow * 128 + (colb ^ ((brow & 7) << 4)));
      acc = __builtin_amdgcn_mfma_f32_32x32x16_f16(a, b, acc, 0, 0, 0);
    }

    // dequant + ds_write B(s+1); compiler inserts counted vmcnt for regs(s+1)
    if (s + 1 < NSTEP) stage_b((s + 1) & 1, w0, z4);
    if (more2) { w0 = n0; z4 = nz; }

    const int tmp = xr0; xr0 = xr1; xr1 = xr2; xr2 = tmp;
  }

  // ---- kh-pair reduction via LDS scratch (xlds base: 40 KB total >= 32 KB needed) ----
  __syncthreads();
  float* red = (float*)&xlds[0][0];
  {
    float4* dst = (float4*)(red + ((size_t)(wid * 64 + lane)) * 16);
    dst[0] = (float4){acc[0],  acc[1],  acc[2],  acc[3]};
    dst[1] = (float4){acc[4],  acc[5],  acc[6],  acc[7]};
    dst[2] = (float4){acc[8],  acc[9],  acc[10], acc[11]};
    dst[3] = (float4){acc[12], acc[13], acc[14], acc[15]};
  }
  __syncthreads();
  if (kh == 0) {
    const float4* src = (const float4*)(red + ((size_t)((wid ^ 1) * 64 + lane)) * 16);
    float4 p0 = src[0], p1 = src[1], p2 = src[2], p3 = src[3];
    // 32x32 C/D: col = lane&31 -> B row -> o; row = (reg&3)+8*(reg>>2)+4*koct -> m
    const int o = ln31 * 128 + c + nh * 4096;
    const int mbase = mh * 32 + 4 * koct;
    float* bp = part + ((size_t)ks * OUT_F + o) * BATCH + mbase;
    *(float4*)(bp +  0) = (float4){acc[0]  + p0.x, acc[1]  + p0.y, acc[2]  + p0.z, acc[3]  + p0.w};
    *(float4*)(bp +  8) = (float4){acc[4]  + p1.x, acc[5]  + p1.y, acc[6]  + p1.z, acc[7]  + p1.w};
    *(float4*)(bp + 16) = (float4){acc[8]  + p2.x, acc[9]  + p2.y, acc[10] + p2.z, acc[11] + p2.w};
    *(float4*)(bp + 24) = (float4){acc[12] + p3.x, acc[13] + p3.y, acc[14] + p3.z, acc[15] + p3.w};
  }
}

// ---- split-K reduce + bias + transpose to out[m][o] ----
__global__ __launch_bounds__(256) void reduce_kernel(const float* __restrict__ part,
                                                     const float* __restrict__ bias,
                                                     float* __restrict__ out)
{
  __shared__ float tile[32][65];
  const int ob = blockIdx.x;          // o-range [ob*32, +32)
  const int t  = threadIdx.x;
  {
    const int ol = t >> 3;            // 0..31
    const int mg = t & 7;             // m-octet
    const int o  = ob * 32 + ol;
    const size_t base = (size_t)o * BATCH + mg * 8;
    float s[8] = {0, 0, 0, 0, 0, 0, 0, 0};
    #pragma unroll
    for (int ks = 0; ks < KS; ++ks) {
      const float* p = part + (size_t)ks * OUT_F * BATCH + base;
      float4 a = *(const float4*)p;
      float4 b = *(const float4*)(p + 4);
      s[0] += a.x; s[1] += a.y; s[2] += a.z; s[3] += a.w;
      s[4] += b.x; s[5] += b.y; s[6] += b.z; s[7] += b.w;
    }
    const float bv = bias[o];
    #pragma unroll
    for (int j = 0; j < 8; ++j) tile[ol][mg * 8 + j] = s[j] + bv;
  }
  __syncthreads();
  {
    const int m  = t >> 2;            // 0..63
    const int og = (t & 3) * 8;       // 0..31
    float r[8];
    #pragma unroll
    for (int j = 0; j < 8; ++j) r[j] = tile[og + j][m];
    float* op = out + (size_t)m * OUT_F + ob * 32 + og;
    *(float4*)op       = (float4){r[0], r[1], r[2], r[3]};
    *(float4*)(op + 4) = (float4){r[4], r[5], r[6], r[7]};
  }
}

// ---- correctness fallback (tiny ws), fp32 ----
__global__ void hqq_fallback_kernel(const float* __restrict__ x, const int* __restrict__ Wq,
                                    const float* __restrict__ scale, const float* __restrict__ zero,
                                    const float* __restrict__ bias, float* __restrict__ out)
{
  int idx = blockIdx.x * blockDim.x + threadIdx.x;
  int b = idx >> 13;
  int o = idx & 8191;
  int g = o >> 7, cc = o & 127;
  int r = g & 31;
  bool hi = (g < 32);
  const int*   wrow = Wq    + (size_t)r  * NGRP + (size_t)cc * IN_F;
  const float* srow = scale + (size_t)cc * IN_F;
  const float* zrow = zero  + (size_t)cc * IN_F;
  const float* xrow = x     + (size_t)b  * IN_F;
  float acc = 0.f;
  for (int k = 0; k < IN_F; ++k) {
    int v = wrow[k];
    float nib = (float)(hi ? (v >> 4) : (v & 15));
    acc += xrow[k] * ((nib - zrow[k]) * srow[k]);
  }
  out[idx] = acc + bias[o];
}

extern "C" void kernel_launch(void* const* d_in, const int* in_sizes, int n_in,
                              void* d_out, int out_size, void* d_ws, size_t ws_size,
                              hipStream_t stream) {
  const float* x     = (const float*)d_in[0];
  const int*   Wq    = (const int*)d_in[1];
  const float* scale = (const float*)d_in[2];
  const float* zero  = (const float*)d_in[3];
  const float* bias  = (const float*)d_in[4];
  float* out = (float*)d_out;

  const size_t xh_bytes   = (size_t)BATCH * IN_F * sizeof(ushort);        // 1 MB
  const size_t sz_bytes   = (size_t)NGRP * 4;                             // 4 MB
  const size_t part_bytes = (size_t)KS * BATCH * OUT_F * sizeof(float);   // 16 MB

  if (ws_size >= xh_bytes + sz_bytes + part_bytes) {
    ushort*   xh   = (ushort*)d_ws;
    uint32_t* szb  = (uint32_t*)((char*)d_ws + xh_bytes);
    float*    part = (float*)((char*)d_ws + xh_bytes + sz_bytes);
    pre_kernel<<<1536, 256, 0, stream>>>(x, xh, scale, zero, szb);
    hqq_gemm_kernel<<<128 * KS, 512, 0, stream>>>(Wq, szb, xh, part);
    reduce_kernel<<<OUT_F / 32, 256, 0, stream>>>(part, bias, out);
  } else {
    hqq_fallback_kernel<<<(BATCH * OUT_F) / 256, 256, 0, stream>>>(x, Wq, scale, zero, bias, out);
  }
}

// Round 19
// 41.172 us; speedup vs baseline: 1.0423x; 1.0423x over previous
//
#include <hip/hip_runtime.h>
#include <stdint.h>

#define OUT_F 8192
#define IN_F  8192
#define NGRP  1048576      // OUT*IN/GS
#define BATCH 64
#define KS    4
#define NSTEP ((IN_F / KS) / 128)   // 16

typedef float f32x4  __attribute__((ext_vector_type(4)));
typedef float f32x16 __attribute__((ext_vector_type(16)));
typedef _Float16 half8_t __attribute__((ext_vector_type(8)));

static __device__ __forceinline__ unsigned int pk_fma_f16(unsigned int a, unsigned int b, unsigned int c) {
  unsigned int d;
  asm("v_pk_fma_f16 %0, %1, %2, %3" : "=v"(d) : "v"(a), "v"(b), "v"(c));
  return d;
}
static __device__ __forceinline__ unsigned int pkrtz(float a, float b) {
  return __builtin_bit_cast(unsigned int, __builtin_amdgcn_cvt_pkrtz(a, b));
}

#define GLL16(g, l)                                                         \
  __builtin_amdgcn_global_load_lds(                                         \
      (const __attribute__((address_space(1))) void*)(g),                   \
      (__attribute__((address_space(3))) void*)(l), 16, 0, 0)

// ---- pre-pass: x fp32 -> f16 only (sz packing fused into gemm) ----
__global__ __launch_bounds__(256) void pre_kernel(const float* __restrict__ x, ushort* __restrict__ xh) {
  const int i = blockIdx.x * 256 + threadIdx.x;   // 512*256 = BATCH*IN_F/4
  float4 v = ((const float4*)x)[i];
  ushort4 o;
  o.x = __builtin_bit_cast(unsigned short, (_Float16)v.x);
  o.y = __builtin_bit_cast(unsigned short, (_Float16)v.y);
  o.z = __builtin_bit_cast(unsigned short, (_Float16)v.z);
  o.w = __builtin_bit_cast(unsigned short, (_Float16)v.w);
  ((ushort4*)xh)[i] = o;
}

// ---- main fused dequant + GEMM (R16 structure; sz read f32 + packed in-register) ----
// grid 512: ks = bid&3 (2048 k each), c = bid>>2. Block owns ALL 64 outputs of column c.
// Wave wid: kh = wid&1 (4 of 8 k-slices), mh = (wid>>1)&1 (32 m), nh = wid>>2 (32 o).
// Final kh-pair sum via LDS scratch. 80 KB LDS -> 2 blocks/CU = 16 waves/CU.
__global__ __launch_bounds__(512, 4) void hqq_gemm_kernel(
    const int* __restrict__ Wq, const float* __restrict__ scale, const float* __restrict__ zero,
    const ushort* __restrict__ xh, float* __restrict__ part)
{
  __shared__ ushort xlds[3][64 * 128];   // 16 KB each
  __shared__ ushort blds[2][64 * 128];   // 16 KB each (B tile; reused as reduce scratch)

  const int t    = threadIdx.x;
  const int bid  = blockIdx.x;
  const int ks   = bid & 3;
  const int c    = bid >> 2;
  const int lane = t & 63;
  const int wid  = t >> 6;               // 0..7
  const int kbase = ks * (IN_F / KS);

  // staging ids: lr = t>>5 (0..15) covers Wq rows lr, lr+16; i0 = 4 k-ints
  const int lr = t >> 5;
  const int i0 = (t & 31) * 4;
  const int* __restrict__ wq0 = Wq + (size_t)lr * NGRP + (size_t)c * IN_F + kbase + i0;
  const int* __restrict__ wq1 = wq0 + (size_t)16 * NGRP;
  const float* __restrict__ scp = scale + (size_t)c * IN_F + kbase + i0;
  const float* __restrict__ zrp = zero  + (size_t)c * IN_F + kbase + i0;
  const int wb0 = (i0 * 2) ^ ((lr & 7) << 4);   // swizzled write byte col; (lr+16)&7==lr&7

  // frag ids (32x32 octants)
  const int kh   = wid & 1;
  const int mh   = (wid >> 1) & 1;
  const int nh   = wid >> 2;
  const int ln31 = lane & 31;
  const int koct = lane >> 5;
  const int arow = mh * 32 + ln31;
  const int brow = nh * 32 + ln31;

  f32x16 acc = {0.f, 0.f, 0.f, 0.f, 0.f, 0.f, 0.f, 0.f,
                0.f, 0.f, 0.f, 0.f, 0.f, 0.f, 0.f, 0.f};

  // x: 2 gll per wave, rows wid*8..+7; source pre-swizzled: LDS[m][b]=x[m][b^((m&7)<<4)]
  auto stage_x = [&](int bi, int s) {
    #pragma unroll
    for (int j = 0; j < 2; ++j) {
      const int m    = wid * 8 + j * 4 + (lane >> 4);
      const int scol = ((lane & 15) * 16) ^ ((m & 7) << 4);
      const ushort* g = xh + (size_t)m * IN_F + kbase + s * 128 + (scol >> 1);
      GLL16(g, &xlds[bi][(wid * 8 + j * 4) * 128]);
    }
  };

  auto ldregs = [&](int s, int4& w0, int4& w1, float4& sc, float4& zr) {
    w0 = *(const int4*)(wq0 + (size_t)s * 128);
    w1 = *(const int4*)(wq1 + (size_t)s * 128);
    sc = *(const float4*)(scp + (size_t)s * 128);
    zr = *(const float4*)(zrp + (size_t)s * 128);
  };

  // f16 magic: 0x5400 | (v<<4) == 64+v  (nibble at mantissa bits [7:4])
  auto stage_b = [&](int bi, const int4& w0, const int4& w1, const float4& sc, const float4& zr) {
    // pack {f16(s), f16(-(64+z)*s)} pairs in-register (was pre-pass work)
    const unsigned s01 = pkrtz(sc.x, sc.y);
    const unsigned z01 = pkrtz(-(64.f + zr.x) * sc.x, -(64.f + zr.y) * sc.y);
    const unsigned s23 = pkrtz(sc.z, sc.w);
    const unsigned z23 = pkrtz(-(64.f + zr.z) * sc.z, -(64.f + zr.w) * sc.w);
    uint8_t* bb = (uint8_t*)&blds[bi][0];
    auto dqrow = [&](const int4& wv, int r) {
      unsigned tt0 = ((unsigned)wv.y << 16) | (unsigned)wv.x;
      unsigned tt1 = ((unsigned)wv.w << 16) | (unsigned)wv.z;
      uint2 hh, ll;
      hh.x = pk_fma_f16((tt0 & 0x00F000F0u) | 0x54005400u, s01, z01);
      hh.y = pk_fma_f16((tt1 & 0x00F000F0u) | 0x54005400u, s23, z23);
      ll.x = pk_fma_f16(((tt0 << 4) & 0x00F000F0u) | 0x54005400u, s01, z01);
      ll.y = pk_fma_f16(((tt1 << 4) & 0x00F000F0u) | 0x54005400u, s23, z23);
      *(uint2*)(bb + r * 256 + wb0)        = hh;   // hi nibble row r
      *(uint2*)(bb + (r + 32) * 256 + wb0) = ll;   // lo nibble row r+32
    };
    dqrow(w0, lr);
    dqrow(w1, lr + 16);
  };

  // ---- prologue ----
  {
    int4 a0, a1; float4 s0, z0;
    ldregs(0, a0, a1, s0, z0);
    stage_b(0, a0, a1, s0, z0);       // compiler waits regs(0)
  }
  stage_x(0, 0);
  stage_x(1, 1);
  int4 w0, w1; float4 sc, zr;
  ldregs(1, w0, w1, sc, zr);          // regs for stage_b(1)

  int xr0 = 0, xr1 = 1, xr2 = 2;

  #pragma unroll 1
  for (int s = 0; s < NSTEP; ++s) {
    // retire compute(s-1) on all waves; make stage_b(s) ds_writes visible.
    asm volatile("s_waitcnt lgkmcnt(0)" ::: "memory");
    __builtin_amdgcn_s_barrier();

    const bool more2 = (s + 2 < NSTEP);
    int4 n0, n1; float4 ns, nz;
    if (more2) {
      stage_x(xr2, s + 2);            // 2 gll
      ldregs(s + 2, n0, n1, ns, nz);  // 4 reg loads
    }

    // in-order vmcnt: wait x(s); newer = [x(s+1)2+regs(s+1)4] + [x(s+2)2+regs(s+2)4]
    if (more2)               asm volatile("s_waitcnt vmcnt(12)" ::: "memory");
    else if (s + 1 < NSTEP)  asm volatile("s_waitcnt vmcnt(6)" ::: "memory");
    else                     asm volatile("s_waitcnt vmcnt(0)" ::: "memory");
    __builtin_amdgcn_sched_barrier(0);

    // compute(s): wave's 4 k-slices; 1 A + 1 B ds_read_b128 + 1 32x32x16 MFMA each
    const uint8_t* xb   = (const uint8_t*)&xlds[xr0][0];
    const uint8_t* bbuf = (const uint8_t*)&blds[s & 1][0];
    #pragma unroll
    for (int j = 0; j < 4; ++j) {
      const int kk   = kh * 4 + j;
      const int colb = (kk * 16 + koct * 8) * 2;
      half8_t a = *(const half8_t*)(xb   + arow * 256 + (colb ^ ((arow & 7) << 4)));
      half8_t b = *(const half8_t*)(bbuf + brow * 256 + (colb ^ ((brow & 7) << 4)));
      acc = __builtin_amdgcn_mfma_f32_32x32x16_f16(a, b, acc, 0, 0, 0);
    }

    // dequant + ds_write B(s+1); compiler inserts counted vmcnt for regs(s+1)
    if (s + 1 < NSTEP) stage_b((s + 1) & 1, w0, w1, sc, zr);
    if (more2) { w0 = n0; w1 = n1; sc = ns; zr = nz; }

    const int tmp = xr0; xr0 = xr1; xr1 = xr2; xr2 = tmp;
  }

  // ---- kh-pair reduction via LDS scratch (blds = 32 KB, exactly fits 8x64x16 f32) ----
  __syncthreads();
  float* red = (float*)&blds[0][0];
  {
    float4* dst = (float4*)(red + ((size_t)(wid * 64 + lane)) * 16);
    dst[0] = (float4){acc[0],  acc[1],  acc[2],  acc[3]};
    dst[1] = (float4){acc[4],  acc[5],  acc[6],  acc[7]};
    dst[2] = (float4){acc[8],  acc[9],  acc[10], acc[11]};
    dst[3] = (float4){acc[12], acc[13], acc[14], acc[15]};
  }
  __syncthreads();
  if (kh == 0) {
    const float4* src = (const float4*)(red + ((size_t)((wid ^ 1) * 64 + lane)) * 16);
    float4 p0 = src[0], p1 = src[1], p2 = src[2], p3 = src[3];
    // 32x32 C/D: col = lane&31 -> B row -> o; row = (reg&3)+8*(reg>>2)+4*koct -> m
    const int o = ln31 * 128 + c + nh * 4096;
    const int mbase = mh * 32 + 4 * koct;
    float* bp = part + ((size_t)ks * OUT_F + o) * BATCH + mbase;
    *(float4*)(bp +  0) = (float4){acc[0]  + p0.x, acc[1]  + p0.y, acc[2]  + p0.z, acc[3]  + p0.w};
    *(float4*)(bp +  8) = (float4){acc[4]  + p1.x, acc[5]  + p1.y, acc[6]  + p1.z, acc[7]  + p1.w};
    *(float4*)(bp + 16) = (float4){acc[8]  + p2.x, acc[9]  + p2.y, acc[10] + p2.z, acc[11] + p2.w};
    *(float4*)(bp + 24) = (float4){acc[12] + p3.x, acc[13] + p3.y, acc[14] + p3.z, acc[15] + p3.w};
  }
}

// ---- split-K reduce + bias + transpose to out[m][o] ----
__global__ __launch_bounds__(256) void reduce_kernel(const float* __restrict__ part,
                                                     const float* __restrict__ bias,
                                                     float* __restrict__ out)
{
  __shared__ float tile[32][65];
  const int ob = blockIdx.x;          // o-range [ob*32, +32)
  const int t  = threadIdx.x;
  {
    const int ol = t >> 3;            // 0..31
    const int mg = t & 7;             // m-octet
    const int o  = ob * 32 + ol;
    const size_t base = (size_t)o * BATCH + mg * 8;
    float s[8] = {0, 0, 0, 0, 0, 0, 0, 0};
    #pragma unroll
    for (int ks = 0; ks < KS; ++ks) {
      const float* p = part + (size_t)ks * OUT_F * BATCH + base;
      float4 a = *(const float4*)p;
      float4 b = *(const float4*)(p + 4);
      s[0] += a.x; s[1] += a.y; s[2] += a.z; s[3] += a.w;
      s[4] += b.x; s[5] += b.y; s[6] += b.z; s[7] += b.w;
    }
    const float bv = bias[o];
    #pragma unroll
    for (int j = 0; j < 8; ++j) tile[ol][mg * 8 + j] = s[j] + bv;
  }
  __syncthreads();
  {
    const int m  = t >> 2;            // 0..63
    const int og = (t & 3) * 8;       // 0..31
    float r[8];
    #pragma unroll
    for (int j = 0; j < 8; ++j) r[j] = tile[og + j][m];
    float* op = out + (size_t)m * OUT_F + ob * 32 + og;
    *(float4*)op       = (float4){r[0], r[1], r[2], r[3]};
    *(float4*)(op + 4) = (float4){r[4], r[5], r[6], r[7]};
  }
}

// ---- correctness fallback (tiny ws), fp32 ----
__global__ void hqq_fallback_kernel(const float* __restrict__ x, const int* __restrict__ Wq,
                                    const float* __restrict__ scale, const float* __restrict__ zero,
                                    const float* __restrict__ bias, float* __restrict__ out)
{
  int idx = blockIdx.x * blockDim.x + threadIdx.x;
  int b = idx >> 13;
  int o = idx & 8191;
  int g = o >> 7, cc = o & 127;
  int r = g & 31;
  bool hi = (g < 32);
  const int*   wrow = Wq    + (size_t)r  * NGRP + (size_t)cc * IN_F;
  const float* srow = scale + (size_t)cc * IN_F;
  const float* zrow = zero  + (size_t)cc * IN_F;
  const float* xrow = x     + (size_t)b  * IN_F;
  float acc = 0.f;
  for (int k = 0; k < IN_F; ++k) {
    int v = wrow[k];
    float nib = (float)(hi ? (v >> 4) : (v & 15));
    acc += xrow[k] * ((nib - zrow[k]) * srow[k]);
  }
  out[idx] = acc + bias[o];
}

extern "C" void kernel_launch(void* const* d_in, const int* in_sizes, int n_in,
                              void* d_out, int out_size, void* d_ws, size_t ws_size,
                              hipStream_t stream) {
  const float* x     = (const float*)d_in[0];
  const int*   Wq    = (const int*)d_in[1];
  const float* scale = (const float*)d_in[2];
  const float* zero  = (const float*)d_in[3];
  const float* bias  = (const float*)d_in[4];
  float* out = (float*)d_out;

  const size_t xh_bytes   = (size_t)BATCH * IN_F * sizeof(ushort);        // 1 MB
  const size_t part_bytes = (size_t)KS * BATCH * OUT_F * sizeof(float);   // 8 MB

  if (ws_size >= xh_bytes + part_bytes) {
    ushort* xh   = (ushort*)d_ws;
    float*  part = (float*)((char*)d_ws + xh_bytes);
    pre_kernel<<<512, 256, 0, stream>>>(x, xh);
    hqq_gemm_kernel<<<128 * KS, 512, 0, stream>>>(Wq, scale, zero, xh, part);
    reduce_kernel<<<OUT_F / 32, 256, 0, stream>>>(part, bias, out);
  } else {
    hqq_fallback_kernel<<<(BATCH * OUT_F) / 256, 256, 0, stream>>>(x, Wq, scale, zero, bias, out);
  }
}

// Round 20
// 40.082 us; speedup vs baseline: 1.0707x; 1.0272x over previous
//
#include <hip/hip_runtime.h>
#include <stdint.h>

#define OUT_F 8192
#define IN_F  8192
#define NGRP  1048576      // OUT*IN/GS
#define BATCH 64
#define KS    4
#define NSTEP ((IN_F / KS) / 128)   // 16

typedef float f32x4  __attribute__((ext_vector_type(4)));
typedef float f32x16 __attribute__((ext_vector_type(16)));
typedef _Float16 half8_t __attribute__((ext_vector_type(8)));

static __device__ __forceinline__ unsigned int pk_fma_f16(unsigned int a, unsigned int b, unsigned int c) {
  unsigned int d;
  asm("v_pk_fma_f16 %0, %1, %2, %3" : "=v"(d) : "v"(a), "v"(b), "v"(c));
  return d;
}
static __device__ __forceinline__ unsigned int pk16(float a, float b) {
  unsigned short ua = __builtin_bit_cast(unsigned short, (_Float16)a);
  unsigned short ub = __builtin_bit_cast(unsigned short, (_Float16)b);
  return (unsigned int)ua | ((unsigned int)ub << 16);
}
static __device__ __forceinline__ unsigned int f2bf_pk(float a, float b) {
  unsigned ua = __builtin_bit_cast(unsigned, a);
  unsigned ub = __builtin_bit_cast(unsigned, b);
  ua = (ua + 0x7fffu + ((ua >> 16) & 1u)) >> 16;   // RNE
  ub = (ub + 0x7fffu + ((ub >> 16) & 1u)) >> 16;
  return ua | (ub << 16);
}

#define GLL16(g, l)                                                         \
  __builtin_amdgcn_global_load_lds(                                         \
      (const __attribute__((address_space(1))) void*)(g),                   \
      (__attribute__((address_space(3))) void*)(l), 16, 0, 0)

// ---- fused pre-pass: x fp32->f16  +  per-2-group {f16x2(s), f16x2(-(64+z)s)} ----
__global__ __launch_bounds__(256) void pre_kernel(const float* __restrict__ x, ushort* __restrict__ xh,
                                                  const float* __restrict__ scale, const float* __restrict__ zero,
                                                  uint32_t* __restrict__ szb) {
  const int b = blockIdx.x;
  if (b < 512) {                      // 512*256 = BATCH*IN_F/4
    const int i = b * 256 + threadIdx.x;
    float4 v = ((const float4*)x)[i];
    ushort4 o;
    o.x = __builtin_bit_cast(unsigned short, (_Float16)v.x);
    o.y = __builtin_bit_cast(unsigned short, (_Float16)v.y);
    o.z = __builtin_bit_cast(unsigned short, (_Float16)v.z);
    o.w = __builtin_bit_cast(unsigned short, (_Float16)v.w);
    ((ushort4*)xh)[i] = o;
  } else {                            // 1024*256 = NGRP/4
    const int i = (b - 512) * 256 + threadIdx.x;
    float4 s = ((const float4*)scale)[i];
    float4 z = ((const float4*)zero)[i];
    uint4 o;
    o.x = pk16(s.x, s.y);
    o.y = pk16(-(64.f + z.x) * s.x, -(64.f + z.y) * s.y);
    o.z = pk16(s.z, s.w);
    o.w = pk16(-(64.f + z.z) * s.z, -(64.f + z.w) * s.w);
    ((uint4*)szb)[i] = o;
  }
}

// ---- main fused dequant + GEMM (R16 structure; bf16 partials) ----
// grid 512: ks = bid&3 (2048 k each), c = bid>>2. Block owns ALL 64 outputs of column c.
// Wave wid: kh = wid&1 (4 of 8 k-slices), mh = (wid>>1)&1 (32 m), nh = wid>>2 (32 o).
// Final kh-pair sum via LDS scratch; partials stored bf16. 80 KB LDS -> 2 blocks/CU.
__global__ __launch_bounds__(512, 4) void hqq_gemm_kernel(
    const int* __restrict__ Wq, const uint32_t* __restrict__ szb,
    const ushort* __restrict__ xh, ushort* __restrict__ partb)
{
  __shared__ ushort xlds[3][64 * 128];   // 16 KB each
  __shared__ ushort blds[2][64 * 128];   // 16 KB each (B tile; reused as reduce scratch)

  const int t    = threadIdx.x;
  const int bid  = blockIdx.x;
  const int ks   = bid & 3;
  const int c    = bid >> 2;
  const int lane = t & 63;
  const int wid  = t >> 6;               // 0..7
  const int kbase = ks * (IN_F / KS);

  // staging ids: lr = t>>5 (0..15) covers Wq rows lr, lr+16; i0 = 4 k-ints
  const int lr = t >> 5;
  const int i0 = (t & 31) * 4;
  const int* __restrict__ wq0 = Wq + (size_t)lr * NGRP + (size_t)c * IN_F + kbase + i0;
  const int* __restrict__ wq1 = wq0 + (size_t)16 * NGRP;
  const uint8_t* __restrict__ szp =
      (const uint8_t*)szb + ((size_t)c * IN_F + kbase + i0) * 4;
  const int wb0 = (i0 * 2) ^ ((lr & 7) << 4);   // swizzled write byte col; (lr+16)&7==lr&7

  // frag ids (32x32 octants)
  const int kh   = wid & 1;
  const int mh   = (wid >> 1) & 1;
  const int nh   = wid >> 2;
  const int ln31 = lane & 31;
  const int koct = lane >> 5;
  const int arow = mh * 32 + ln31;
  const int brow = nh * 32 + ln31;

  f32x16 acc = {0.f, 0.f, 0.f, 0.f, 0.f, 0.f, 0.f, 0.f,
                0.f, 0.f, 0.f, 0.f, 0.f, 0.f, 0.f, 0.f};

  // x: 2 gll per wave, rows wid*8..+7; source pre-swizzled: LDS[m][b]=x[m][b^((m&7)<<4)]
  auto stage_x = [&](int bi, int s) {
    #pragma unroll
    for (int j = 0; j < 2; ++j) {
      const int m    = wid * 8 + j * 4 + (lane >> 4);
      const int scol = ((lane & 15) * 16) ^ ((m & 7) << 4);
      const ushort* g = xh + (size_t)m * IN_F + kbase + s * 128 + (scol >> 1);
      GLL16(g, &xlds[bi][(wid * 8 + j * 4) * 128]);
    }
  };

  auto ldregs = [&](int s, int4& w0, int4& w1, uint4& z4) {
    w0 = *(const int4*)(wq0 + (size_t)s * 128);
    w1 = *(const int4*)(wq1 + (size_t)s * 128);
    z4 = *(const uint4*)(szp + (size_t)s * 512);
  };

  // f16 magic: 0x5400 | (v<<4) == 64+v  (nibble at mantissa bits [7:4])
  auto stage_b = [&](int bi, const int4& w0, const int4& w1, const uint4& z4) {
    uint8_t* bb = (uint8_t*)&blds[bi][0];
    auto dqrow = [&](const int4& wv, int r) {
      unsigned tt0 = ((unsigned)wv.y << 16) | (unsigned)wv.x;
      unsigned tt1 = ((unsigned)wv.w << 16) | (unsigned)wv.z;
      uint2 hh, ll;
      hh.x = pk_fma_f16((tt0 & 0x00F000F0u) | 0x54005400u, z4.x, z4.y);
      hh.y = pk_fma_f16((tt1 & 0x00F000F0u) | 0x54005400u, z4.z, z4.w);
      ll.x = pk_fma_f16(((tt0 << 4) & 0x00F000F0u) | 0x54005400u, z4.x, z4.y);
      ll.y = pk_fma_f16(((tt1 << 4) & 0x00F000F0u) | 0x54005400u, z4.z, z4.w);
      *(uint2*)(bb + r * 256 + wb0)        = hh;   // hi nibble row r
      *(uint2*)(bb + (r + 32) * 256 + wb0) = ll;   // lo nibble row r+32
    };
    dqrow(w0, lr);
    dqrow(w1, lr + 16);
  };

  // ---- prologue ----
  {
    int4 a0, a1; uint4 z0;
    ldregs(0, a0, a1, z0);
    stage_b(0, a0, a1, z0);           // compiler waits regs(0)
  }
  stage_x(0, 0);
  stage_x(1, 1);
  int4 w0, w1; uint4 z4;
  ldregs(1, w0, w1, z4);              // regs for stage_b(1)

  int xr0 = 0, xr1 = 1, xr2 = 2;

  #pragma unroll 1
  for (int s = 0; s < NSTEP; ++s) {
    // retire compute(s-1) on all waves; make stage_b(s) ds_writes visible.
    asm volatile("s_waitcnt lgkmcnt(0)" ::: "memory");
    __builtin_amdgcn_s_barrier();

    const bool more2 = (s + 2 < NSTEP);
    int4 n0, n1; uint4 nz;
    if (more2) {
      stage_x(xr2, s + 2);            // 2 gll
      ldregs(s + 2, n0, n1, nz);      // 3 reg loads
    }

    // in-order vmcnt: wait x(s); newer = [x(s+1)2+regs(s+1)3] + [x(s+2)2+regs(s+2)3]
    if (more2)               asm volatile("s_waitcnt vmcnt(10)" ::: "memory");
    else if (s + 1 < NSTEP)  asm volatile("s_waitcnt vmcnt(5)" ::: "memory");
    else                     asm volatile("s_waitcnt vmcnt(0)" ::: "memory");
    __builtin_amdgcn_sched_barrier(0);

    // compute(s): wave's 4 k-slices; 1 A + 1 B ds_read_b128 + 1 32x32x16 MFMA each
    const uint8_t* xb   = (const uint8_t*)&xlds[xr0][0];
    const uint8_t* bbuf = (const uint8_t*)&blds[s & 1][0];
    #pragma unroll
    for (int j = 0; j < 4; ++j) {
      const int kk   = kh * 4 + j;
      const int colb = (kk * 16 + koct * 8) * 2;
      half8_t a = *(const half8_t*)(xb   + arow * 256 + (colb ^ ((arow & 7) << 4)));
      half8_t b = *(const half8_t*)(bbuf + brow * 256 + (colb ^ ((brow & 7) << 4)));
      acc = __builtin_amdgcn_mfma_f32_32x32x16_f16(a, b, acc, 0, 0, 0);
    }

    // dequant + ds_write B(s+1); compiler inserts counted vmcnt for regs(s+1)
    if (s + 1 < NSTEP) stage_b((s + 1) & 1, w0, w1, z4);
    if (more2) { w0 = n0; w1 = n1; z4 = nz; }

    const int tmp = xr0; xr0 = xr1; xr1 = xr2; xr2 = tmp;
  }

  // ---- kh-pair reduction via LDS scratch (blds = 32 KB, exactly fits 8x64x16 f32) ----
  __syncthreads();
  float* red = (float*)&blds[0][0];
  {
    float4* dst = (float4*)(red + ((size_t)(wid * 64 + lane)) * 16);
    dst[0] = (float4){acc[0],  acc[1],  acc[2],  acc[3]};
    dst[1] = (float4){acc[4],  acc[5],  acc[6],  acc[7]};
    dst[2] = (float4){acc[8],  acc[9],  acc[10], acc[11]};
    dst[3] = (float4){acc[12], acc[13], acc[14], acc[15]};
  }
  __syncthreads();
  if (kh == 0) {
    const float4* src = (const float4*)(red + ((size_t)((wid ^ 1) * 64 + lane)) * 16);
    float4 p0 = src[0], p1 = src[1], p2 = src[2], p3 = src[3];
    // 32x32 C/D: col = lane&31 -> B row -> o; row = (reg&3)+8*(reg>>2)+4*koct -> m
    const int o = ln31 * 128 + c + nh * 4096;
    const int mbase = mh * 32 + 4 * koct;
    ushort* bp = partb + ((size_t)ks * OUT_F + o) * BATCH + mbase;
    uint2 q;
    q.x = f2bf_pk(acc[0]  + p0.x, acc[1]  + p0.y);
    q.y = f2bf_pk(acc[2]  + p0.z, acc[3]  + p0.w);
    *(uint2*)(bp + 0) = q;
    q.x = f2bf_pk(acc[4]  + p1.x, acc[5]  + p1.y);
    q.y = f2bf_pk(acc[6]  + p1.z, acc[7]  + p1.w);
    *(uint2*)(bp + 8) = q;
    q.x = f2bf_pk(acc[8]  + p2.x, acc[9]  + p2.y);
    q.y = f2bf_pk(acc[10] + p2.z, acc[11] + p2.w);
    *(uint2*)(bp + 16) = q;
    q.x = f2bf_pk(acc[12] + p3.x, acc[13] + p3.y);
    q.y = f2bf_pk(acc[14] + p3.z, acc[15] + p3.w);
    *(uint2*)(bp + 24) = q;
  }
}

// ---- split-K reduce (bf16 partials) + bias + transpose to out[m][o] ----
__global__ __launch_bounds__(256) void reduce_kernel(const ushort* __restrict__ partb,
                                                     const float* __restrict__ bias,
                                                     float* __restrict__ out)
{
  __shared__ float tile[32][65];
  const int ob = blockIdx.x;          // o-range [ob*32, +32)
  const int t  = threadIdx.x;
  {
    const int ol = t >> 3;            // 0..31
    const int mg = t & 7;             // m-octet
    const int o  = ob * 32 + ol;
    const size_t base = (size_t)o * BATCH + mg * 8;
    float s[8] = {0, 0, 0, 0, 0, 0, 0, 0};
    #pragma unroll
    for (int ks = 0; ks < KS; ++ks) {
      const ushort* p = partb + (size_t)ks * OUT_F * BATCH + base;
      uint4 v = *(const uint4*)p;     // 8 bf16
      s[0] += __uint_as_float(v.x << 16); s[1] += __uint_as_float(v.x & 0xffff0000u);
      s[2] += __uint_as_float(v.y << 16); s[3] += __uint_as_float(v.y & 0xffff0000u);
      s[4] += __uint_as_float(v.z << 16); s[5] += __uint_as_float(v.z & 0xffff0000u);
      s[6] += __uint_as_float(v.w << 16); s[7] += __uint_as_float(v.w & 0xffff0000u);
    }
    const float bv = bias[o];
    #pragma unroll
    for (int j = 0; j < 8; ++j) tile[ol][mg * 8 + j] = s[j] + bv;
  }
  __syncthreads();
  {
    const int m  = t >> 2;            // 0..63
    const int og = (t & 3) * 8;       // 0..31
    float r[8];
    #pragma unroll
    for (int j = 0; j < 8; ++j) r[j] = tile[og + j][m];
    float* op = out + (size_t)m * OUT_F + ob * 32 + og;
    *(float4*)op       = (float4){r[0], r[1], r[2], r[3]};
    *(float4*)(op + 4) = (float4){r[4], r[5], r[6], r[7]};
  }
}

// ---- correctness fallback (tiny ws), fp32 ----
__global__ void hqq_fallback_kernel(const float* __restrict__ x, const int* __restrict__ Wq,
                                    const float* __restrict__ scale, const float* __restrict__ zero,
                                    const float* __restrict__ bias, float* __restrict__ out)
{
  int idx = blockIdx.x * blockDim.x + threadIdx.x;
  int b = idx >> 13;
  int o = idx & 8191;
  int g = o >> 7, cc = o & 127;
  int r = g & 31;
  bool hi = (g < 32);
  const int*   wrow = Wq    + (size_t)r  * NGRP + (size_t)cc * IN_F;
  const float* srow = scale + (size_t)cc * IN_F;
  const float* zrow = zero  + (size_t)cc * IN_F;
  const float* xrow = x     + (size_t)b  * IN_F;
  float acc = 0.f;
  for (int k = 0; k < IN_F; ++k) {
    int v = wrow[k];
    float nib = (float)(hi ? (v >> 4) : (v & 15));
    acc += xrow[k] * ((nib - zrow[k]) * srow[k]);
  }
  out[idx] = acc + bias[o];
}

extern "C" void kernel_launch(void* const* d_in, const int* in_sizes, int n_in,
                              void* d_out, int out_size, void* d_ws, size_t ws_size,
                              hipStream_t stream) {
  const float* x     = (const float*)d_in[0];
  const int*   Wq    = (const int*)d_in[1];
  const float* scale = (const float*)d_in[2];
  const float* zero  = (const float*)d_in[3];
  const float* bias  = (const float*)d_in[4];
  float* out = (float*)d_out;

  const size_t xh_bytes   = (size_t)BATCH * IN_F * sizeof(ushort);        // 1 MB
  const size_t sz_bytes   = (size_t)NGRP * 4;                             // 4 MB
  const size_t part_bytes = (size_t)KS * BATCH * OUT_F * sizeof(ushort);  // 4 MB

  if (ws_size >= xh_bytes + sz_bytes + part_bytes) {
    ushort*   xh    = (ushort*)d_ws;
    uint32_t* szb   = (uint32_t*)((char*)d_ws + xh_bytes);
    ushort*   partb = (ushort*)((char*)d_ws + xh_bytes + sz_bytes);
    pre_kernel<<<1536, 256, 0, stream>>>(x, xh, scale, zero, szb);
    hqq_gemm_kernel<<<128 * KS, 512, 0, stream>>>(Wq, szb, xh, partb);
    reduce_kernel<<<OUT_F / 32, 256, 0, stream>>>(partb, bias, out);
  } else {
    hqq_fallback_kernel<<<(BATCH * OUT_F) / 256, 256, 0, stream>>>(x, Wq, scale, zero, bias, out);
  }
}